// Round 3
// baseline (802.354 us; speedup 1.0000x reference)
//
#include <hip/hip_runtime.h>
#include <stdint.h>

// Problem constants (B=4, L=1024 -> N=4096 tokens)
#define N_TOK 4096
#define D_DIM 1024
#define E_EXP 8
#define H_DIM 4096
#define MAX_SCHED 72   // max sum of ceil(ne/128) over experts = 64+7, +1 safety

typedef __attribute__((ext_vector_type(8))) short v8s;   // 8 x bf16 (4 VGPRs) MFMA A/B frag
typedef __attribute__((ext_vector_type(4))) float v4f;   // MFMA C/D frag
typedef __attribute__((ext_vector_type(4))) unsigned short u16x4;

static __device__ __forceinline__ unsigned short f2bf(float f) {
    union { float f; unsigned int u; } c; c.f = f;
    unsigned int u = c.u;
    u += 0x7fffu + ((u >> 16) & 1u);   // RNE
    return (unsigned short)(u >> 16);
}
static __device__ __forceinline__ float bf2f(unsigned short h) {
    union { unsigned int u; float f; } c; c.u = ((unsigned int)h) << 16;
    return c.f;
}

// fast tanh-gelu via hw exp: tanh(u) = 1 - 2/(1+e^{2u}); exact at +-inf saturation
static __device__ __forceinline__ float gelu_fast(float x) {
    float u = 0.7978845608028654f * (x + 0.044715f * x * x * x);
    float t = 1.0f - 2.0f / (1.0f + __expf(2.0f * u));
    return 0.5f * x * (1.0f + t);
}

#define GLDS16(g, l)                                                                     \
    __builtin_amdgcn_global_load_lds((const __attribute__((address_space(1))) void*)(g), \
                                     (__attribute__((address_space(3))) void*)(l), 16, 0, 0)

// ---------------- transpose + fp32->bf16: in[e][r][c] -> out[e][c][r], 64x64 tiles ----------------
__global__ __launch_bounds__(256) void transpose_cvt2(const float* __restrict__ in,
                                                      unsigned short* __restrict__ out,
                                                      int R, int C) {
    __shared__ unsigned short tT[64][68];   // [col][row], stride 68 keeps 8B alignment
    int e = blockIdx.z;
    const float* src = in + (size_t)e * R * C;
    unsigned short* dst = out + (size_t)e * R * C;
    int c0 = blockIdx.x * 64, r0 = blockIdx.y * 64;
    int tid = threadIdx.x;
    int col4 = tid & 15, row = tid >> 4;
#pragma unroll
    for (int rr = 0; rr < 4; rr++) {
        int r = rr * 16 + row;
        float4 v = *(const float4*)(src + (size_t)(r0 + r) * C + c0 + col4 * 4);
        tT[col4 * 4 + 0][r] = f2bf(v.x);
        tT[col4 * 4 + 1][r] = f2bf(v.y);
        tT[col4 * 4 + 2][r] = f2bf(v.z);
        tT[col4 * 4 + 3][r] = f2bf(v.w);
    }
    __syncthreads();
    int r4 = tid & 15, cloc = tid >> 4;
#pragma unroll
    for (int cc = 0; cc < 4; cc++) {
        int c = cc * 16 + cloc;
        u16x4 o = *(const u16x4*)(&tT[c][r4 * 4]);
        *(u16x4*)(dst + (size_t)(c0 + c) * R + r0 + r4 * 4) = o;
    }
}

// ---------------- x fp32 -> bf16 ----------------
__global__ void cvt_x_kernel(const float* __restrict__ x, unsigned short* __restrict__ xb, int n4) {
    int i = blockIdx.x * blockDim.x + threadIdx.x;
    if (i < n4) {
        float4 v = ((const float4*)x)[i];
        u16x4 o;
        o.x = f2bf(v.x); o.y = f2bf(v.y); o.z = f2bf(v.z); o.w = f2bf(v.w);
        ((u16x4*)xb)[i] = o;
    }
}

// ---------------- router: fp32 logits, top-2, softmax, counts ----------------
__global__ void router_kernel(const float* __restrict__ x, const float* __restrict__ Wg,
                              const float* __restrict__ bg, float* __restrict__ logits_out,
                              int* __restrict__ tok_e, float* __restrict__ tok_w,
                              int* __restrict__ counts) {
    int wave = threadIdx.x >> 6;
    int lane = threadIdx.x & 63;
    int t = blockIdx.x * 4 + wave;
    if (t >= N_TOK) return;
    const float* xr = x + (size_t)t * D_DIM;
    float acc[8];
#pragma unroll
    for (int e = 0; e < 8; e++) acc[e] = 0.0f;
    for (int d = lane; d < D_DIM; d += 64) {
        float xv = xr[d];
        const float* wr = Wg + d * 8;
        float4 w0 = *(const float4*)wr;
        float4 w1 = *(const float4*)(wr + 4);
        acc[0] += xv * w0.x; acc[1] += xv * w0.y; acc[2] += xv * w0.z; acc[3] += xv * w0.w;
        acc[4] += xv * w1.x; acc[5] += xv * w1.y; acc[6] += xv * w1.z; acc[7] += xv * w1.w;
    }
#pragma unroll
    for (int m = 1; m < 64; m <<= 1) {
#pragma unroll
        for (int e = 0; e < 8; e++) acc[e] += __shfl_xor(acc[e], m, 64);
    }
    if (lane == 0) {
        float lg[8];
#pragma unroll
        for (int e = 0; e < 8; e++) {
            lg[e] = acc[e] + bg[e];
            logits_out[t * 8 + e] = lg[e];
        }
        int i0 = 0; float v0 = lg[0];
        for (int e = 1; e < 8; e++) if (lg[e] > v0) { v0 = lg[e]; i0 = e; }
        int i1 = (i0 == 0) ? 1 : 0; float v1 = lg[i1];
        for (int e = 0; e < 8; e++) {
            if (e == i0 || e == i1) continue;
            if (lg[e] > v1) { v1 = lg[e]; i1 = e; }
        }
        float e1 = expf(v1 - v0);
        float inv = 1.0f / (1.0f + e1);
        tok_e[2 * t]     = i0; tok_w[2 * t]     = inv;
        tok_e[2 * t + 1] = i1; tok_w[2 * t + 1] = e1 * inv;
        atomicAdd(&counts[i0], 1);
        atomicAdd(&counts[i1], 1);
    }
}

// ---------------- exclusive prefix over 8 counts + compact (e, mblk) schedule ----------------
// sched[0] = #entries; sched[1+i] = (e << 16) | mblk. Blocks beyond #entries exit at the
// TAIL of dispatch order, so the CP never interleaves empty blocks with real ones.
__global__ void prefix_kernel(const int* __restrict__ counts, int* __restrict__ offsets,
                              int* __restrict__ sched) {
    if (threadIdx.x == 0) {
        int s = 0, idx = 0;
        for (int e = 0; e < E_EXP; e++) {
            offsets[e] = s;
            int ne = counts[e];
            s += ne;
            int nm = (ne + 127) >> 7;
            for (int m = 0; m < nm; m++) sched[1 + idx++] = (e << 16) | m;
        }
        sched[0] = idx;
    }
}

// ---------------- fill per-expert token/weight lists (+slot map) ----------------
__global__ void fill_kernel(const int* __restrict__ tok_e, const float* __restrict__ tok_w,
                            const int* __restrict__ offsets, int* __restrict__ cursors,
                            int* __restrict__ list_tok, float* __restrict__ list_w,
                            int* __restrict__ slot_of) {
    int t = blockIdx.x * blockDim.x + threadIdx.x;
    if (t < N_TOK) {
#pragma unroll
        for (int k = 0; k < 2; k++) {
            int e = tok_e[2 * t + k];
            int pos = atomicAdd(&cursors[e], 1);
            int idx = offsets[e] + pos;
            list_tok[idx] = t;
            list_w[idx] = tok_w[2 * t + k];
            slot_of[2 * t + k] = idx;
        }
    }
}

// ============ GEMM core notes ============
// 128x128 tile, BK=64, 4 waves (2x2 of 64x64), mfma_f32_16x16x32_bf16.
// Grid is COMPACTED: blockIdx.y indexes a device-built schedule of real (e, mblk)
// pairs, so every dispatched block (except a short tail) does real work -> CU slots
// fill with real blocks and wave-level latency hiding actually happens.
// Staging: global_load_lds width=16 into DOUBLE-BUFFERED LDS (2 x 32 KB).
// K-loop: issue STAGE(tile k+1) into buf^1, compute tile k from buf, ONE
// __syncthreads() (vmcnt(0)+lgkmcnt(0)+barrier) per iteration.
// XOR swizzle: 16B-chunk g of row r is stored at chunk (g ^ (r&7)); applied on the
// per-lane GLOBAL gather address so the LDS dest stays base + lane*16 (glds req).
// Fragment read: chunk = (kstep*4+q) ^ (r16&7) -> banks perfectly balanced.

// ---------------- GEMM1: Hbuf[slot][H] = gelu(X[tok] @ w1[e] + b1[e]) ----------------
__global__ __launch_bounds__(256) void gemm1_kernel(
    const unsigned short* __restrict__ xb, const unsigned short* __restrict__ w1T,
    const float* __restrict__ b1, const int* __restrict__ counts,
    const int* __restrict__ offsets, const int* __restrict__ list_tok,
    const int* __restrict__ sched, unsigned short* __restrict__ Hbuf) {
    int sm = blockIdx.y;
    if (sm >= sched[0]) return;
    int se = sched[1 + sm];
    int e = se >> 16, mblk = se & 0xffff;
    int ne = counts[e];
    int nblk = blockIdx.x;
    int off = offsets[e];

    __shared__ unsigned short lA[2][128 * 64];
    __shared__ unsigned short lB[2][128 * 64];

    int tid = threadIdx.x;
    int lane = tid & 63, wv = tid >> 6;
    int wm = wv >> 1, wn = wv & 1;
    int q = lane >> 4, r16 = lane & 15;
    int lrow = lane >> 3, cs = lane & 7, g = cs ^ lrow;

    const char* aga[4];
    const char* bga[4];
#pragma unroll
    for (int t = 0; t < 4; t++) {
        int ra = wv * 32 + t * 8 + lrow;
        int mrow = mblk * 128 + ra;
        int tok = (mrow < ne) ? list_tok[off + mrow] : list_tok[off];
        aga[t] = (const char*)(xb + (size_t)tok * D_DIM) + g * 16;
        int rb = nblk * 128 + wv * 32 + t * 8 + lrow;
        bga[t] = (const char*)(w1T + ((size_t)e * H_DIM + rb) * D_DIM) + g * 16;
    }

    v4f acc[4][4];
#pragma unroll
    for (int i = 0; i < 4; i++)
#pragma unroll
        for (int j = 0; j < 4; j++) acc[i][j] = (v4f)(0.0f);

    // prologue: stage tile 0 into buffer 0
#pragma unroll
    for (int t = 0; t < 4; t++)
        GLDS16(aga[t], &lA[0][(wv * 32 + t * 8) * 64]);
#pragma unroll
    for (int t = 0; t < 4; t++)
        GLDS16(bga[t], &lB[0][(wv * 32 + t * 8) * 64]);
    __syncthreads();

    int cur = 0;
    for (int k0 = 0; k0 < D_DIM; k0 += 64) {
        if (k0 + 64 < D_DIM) {   // prefetch next tile into the other buffer
#pragma unroll
            for (int t = 0; t < 4; t++)
                GLDS16(aga[t] + (k0 + 64) * 2, &lA[cur ^ 1][(wv * 32 + t * 8) * 64]);
#pragma unroll
            for (int t = 0; t < 4; t++)
                GLDS16(bga[t] + (k0 + 64) * 2, &lB[cur ^ 1][(wv * 32 + t * 8) * 64]);
        }
        const unsigned short* A = lA[cur];
        const unsigned short* B = lB[cur];
#pragma unroll
        for (int s = 0; s < 2; s++) {
            v8s af[4], bf[4];
#pragma unroll
            for (int i = 0; i < 4; i++)
                af[i] = *(const v8s*)(&A[(wm * 64 + i * 16 + r16) * 64 + (((s * 4 + q) ^ (r16 & 7)) * 8)]);
#pragma unroll
            for (int j = 0; j < 4; j++)
                bf[j] = *(const v8s*)(&B[(wn * 64 + j * 16 + r16) * 64 + (((s * 4 + q) ^ (r16 & 7)) * 8)]);
#pragma unroll
            for (int i = 0; i < 4; i++)
#pragma unroll
                for (int j = 0; j < 4; j++)
                    acc[i][j] = __builtin_amdgcn_mfma_f32_16x16x32_bf16(af[i], bf[j], acc[i][j], 0, 0, 0);
        }
        __syncthreads();   // drains vmcnt(0)+lgkmcnt(0): next tile resident, buf reads done
        cur ^= 1;
    }

#pragma unroll
    for (int j = 0; j < 4; j++) {
        int col = nblk * 128 + wn * 64 + j * 16 + r16;
        float bias = b1[e * H_DIM + col];
#pragma unroll
        for (int i = 0; i < 4; i++) {
#pragma unroll
            for (int r = 0; r < 4; r++) {
                int m = mblk * 128 + wm * 64 + i * 16 + q * 4 + r;
                if (m < ne) {
                    float v = acc[i][j][r] + bias;
                    Hbuf[(size_t)(off + m) * H_DIM + col] = f2bf(gelu_fast(v));
                }
            }
        }
    }
}

// ---------------- GEMM2: Ybuf[slot][D] = w_slot * (Hbuf[slot] @ w2[e] + b2[e]) (bf16) ----------------
__global__ __launch_bounds__(256) void gemm2_kernel(
    const unsigned short* __restrict__ Hbuf, const unsigned short* __restrict__ w2T,
    const float* __restrict__ b2, const int* __restrict__ counts,
    const int* __restrict__ offsets, const float* __restrict__ list_w,
    const int* __restrict__ sched, unsigned short* __restrict__ Ybuf) {
    int sm = blockIdx.y;
    if (sm >= sched[0]) return;
    int se = sched[1 + sm];
    int e = se >> 16, mblk = se & 0xffff;
    int ne = counts[e];
    int nblk = blockIdx.x;
    int off = offsets[e];

    __shared__ unsigned short lA[2][128 * 64];
    __shared__ unsigned short lB[2][128 * 64];

    int tid = threadIdx.x;
    int lane = tid & 63, wv = tid >> 6;
    int wm = wv >> 1, wn = wv & 1;
    int q = lane >> 4, r16 = lane & 15;
    int lrow = lane >> 3, cs = lane & 7, g = cs ^ lrow;

    const char* aga[4];
    const char* bga[4];
#pragma unroll
    for (int t = 0; t < 4; t++) {
        int ra = wv * 32 + t * 8 + lrow;
        int mrow = mblk * 128 + ra;
        int arow = (mrow < ne) ? mrow : 0;
        aga[t] = (const char*)(Hbuf + (size_t)(off + arow) * H_DIM) + g * 16;
        int rb = nblk * 128 + wv * 32 + t * 8 + lrow;
        bga[t] = (const char*)(w2T + ((size_t)e * D_DIM + rb) * H_DIM) + g * 16;
    }

    v4f acc[4][4];
#pragma unroll
    for (int i = 0; i < 4; i++)
#pragma unroll
        for (int j = 0; j < 4; j++) acc[i][j] = (v4f)(0.0f);

    // prologue: stage tile 0 into buffer 0
#pragma unroll
    for (int t = 0; t < 4; t++)
        GLDS16(aga[t], &lA[0][(wv * 32 + t * 8) * 64]);
#pragma unroll
    for (int t = 0; t < 4; t++)
        GLDS16(bga[t], &lB[0][(wv * 32 + t * 8) * 64]);
    __syncthreads();

    int cur = 0;
    for (int k0 = 0; k0 < H_DIM; k0 += 64) {
        if (k0 + 64 < H_DIM) {   // prefetch next tile into the other buffer
#pragma unroll
            for (int t = 0; t < 4; t++)
                GLDS16(aga[t] + (k0 + 64) * 2, &lA[cur ^ 1][(wv * 32 + t * 8) * 64]);
#pragma unroll
            for (int t = 0; t < 4; t++)
                GLDS16(bga[t] + (k0 + 64) * 2, &lB[cur ^ 1][(wv * 32 + t * 8) * 64]);
        }
        const unsigned short* A = lA[cur];
        const unsigned short* B = lB[cur];
#pragma unroll
        for (int s = 0; s < 2; s++) {
            v8s af[4], bf[4];
#pragma unroll
            for (int i = 0; i < 4; i++)
                af[i] = *(const v8s*)(&A[(wm * 64 + i * 16 + r16) * 64 + (((s * 4 + q) ^ (r16 & 7)) * 8)]);
#pragma unroll
            for (int j = 0; j < 4; j++)
                bf[j] = *(const v8s*)(&B[(wn * 64 + j * 16 + r16) * 64 + (((s * 4 + q) ^ (r16 & 7)) * 8)]);
#pragma unroll
            for (int i = 0; i < 4; i++)
#pragma unroll
                for (int j = 0; j < 4; j++)
                    acc[i][j] = __builtin_amdgcn_mfma_f32_16x16x32_bf16(af[i], bf[j], acc[i][j], 0, 0, 0);
        }
        __syncthreads();
        cur ^= 1;
    }

    float bias[4];
#pragma unroll
    for (int j = 0; j < 4; j++)
        bias[j] = b2[e * D_DIM + nblk * 128 + wn * 64 + j * 16 + r16];
#pragma unroll
    for (int i = 0; i < 4; i++) {
#pragma unroll
        for (int r = 0; r < 4; r++) {
            int m = mblk * 128 + wm * 64 + i * 16 + q * 4 + r;
            if (m < ne) {
                int idx = off + m;
                float wgt = list_w[idx];
                unsigned short* yrow = Ybuf + (size_t)idx * D_DIM + nblk * 128 + wn * 64 + r16;
#pragma unroll
                for (int j = 0; j < 4; j++)
                    yrow[j * 16] = f2bf(wgt * (acc[i][j][r] + bias[j]));
            }
        }
    }
}

// ---------------- combine: out[t] = Ybuf[slot_a] + Ybuf[slot_b] ----------------
__global__ void combine_kernel(const unsigned short* __restrict__ Ybuf,
                               const int* __restrict__ slot_of, float* __restrict__ out) {
    int t = blockIdx.x;
    int sa = slot_of[2 * t], sb = slot_of[2 * t + 1];
    const u16x4* ya = (const u16x4*)(Ybuf + (size_t)sa * D_DIM);
    const u16x4* yb = (const u16x4*)(Ybuf + (size_t)sb * D_DIM);
    float4* o = (float4*)(out + (size_t)t * D_DIM);
    int i = threadIdx.x;   // 256 threads x float4 = 1024 floats
    u16x4 a = ya[i], b = yb[i];
    float4 r;
    r.x = bf2f(a.x) + bf2f(b.x);
    r.y = bf2f(a.y) + bf2f(b.y);
    r.z = bf2f(a.z) + bf2f(b.z);
    r.w = bf2f(a.w) + bf2f(b.w);
    o[i] = r;
}

// ---------------- launch ----------------
extern "C" void kernel_launch(void* const* d_in, const int* in_sizes, int n_in,
                              void* d_out, int out_size, void* d_ws, size_t ws_size,
                              hipStream_t stream) {
    const float* x  = (const float*)d_in[0];
    const float* Wg = (const float*)d_in[1];
    const float* bg = (const float*)d_in[2];
    const float* w1 = (const float*)d_in[3];
    const float* b1 = (const float*)d_in[4];
    const float* w2 = (const float*)d_in[5];
    const float* b2 = (const float*)d_in[6];

    float* out = (float*)d_out;                       // [N_TOK * D_DIM]
    float* logits = out + (size_t)N_TOK * D_DIM;      // [N_TOK * E_EXP]

    char* ws = (char*)d_ws;
    // workspace layout (bytes)
    const size_t o_counts  = 0;                         // 8 i32
    const size_t o_cursors = 32;                        // 8 i32
    const size_t o_offsets = 64;                        // 8 i32
    const size_t o_toke    = 128;                       // 8192 i32
    const size_t o_tokw    = o_toke + 32768;
    const size_t o_ltok    = o_tokw + 32768;            // 8448 i32
    const size_t o_lw      = o_ltok + 33792;
    const size_t o_slot    = o_lw + 33792;              // 8192 i32
    const size_t o_sched   = o_slot + 32768;            // 1 + 72 i32 (compact schedule)
    const size_t o_xb      = 196608;                                      // 8 MiB
    const size_t o_w1T     = o_xb + (size_t)N_TOK * D_DIM * 2;            // 64 MiB
    const size_t o_w2T     = o_w1T + (size_t)E_EXP * D_DIM * H_DIM * 2;   // 64 MiB
    const size_t o_Hbuf    = o_w2T + (size_t)E_EXP * D_DIM * H_DIM * 2;   // 64 MiB
    const size_t o_Ybuf    = o_Hbuf + (size_t)8192 * H_DIM * 2;           // 16 MiB

    int*            counts  = (int*)(ws + o_counts);
    int*            cursors = (int*)(ws + o_cursors);
    int*            offs    = (int*)(ws + o_offsets);
    int*            tok_e   = (int*)(ws + o_toke);
    float*          tok_w   = (float*)(ws + o_tokw);
    int*            ltok    = (int*)(ws + o_ltok);
    float*          lw      = (float*)(ws + o_lw);
    int*            slot_of = (int*)(ws + o_slot);
    int*            sched   = (int*)(ws + o_sched);
    unsigned short* xb      = (unsigned short*)(ws + o_xb);
    unsigned short* w1T     = (unsigned short*)(ws + o_w1T);
    unsigned short* w2T     = (unsigned short*)(ws + o_w2T);
    unsigned short* Hbuf    = (unsigned short*)(ws + o_Hbuf);
    unsigned short* Ybuf    = (unsigned short*)(ws + o_Ybuf);

    (void)hipMemsetAsync(ws, 0, 128, stream);   // counts/cursors/offsets

    // w1 [E][D][H] -> w1T [E][H][D]; w2 [E][H][D] -> w2T [E][D][H]
    transpose_cvt2<<<dim3(H_DIM / 64, D_DIM / 64, E_EXP), 256, 0, stream>>>(w1, w1T, D_DIM, H_DIM);
    transpose_cvt2<<<dim3(D_DIM / 64, H_DIM / 64, E_EXP), 256, 0, stream>>>(w2, w2T, H_DIM, D_DIM);
    cvt_x_kernel<<<(N_TOK * D_DIM / 4 + 255) / 256, 256, 0, stream>>>(x, xb, N_TOK * D_DIM / 4);

    router_kernel<<<N_TOK / 4, 256, 0, stream>>>(x, Wg, bg, logits, tok_e, tok_w, counts);
    prefix_kernel<<<1, 64, 0, stream>>>(counts, offs, sched);
    fill_kernel<<<N_TOK / 256, 256, 0, stream>>>(tok_e, tok_w, offs, cursors, ltok, lw, slot_of);

    gemm1_kernel<<<dim3(H_DIM / 128, MAX_SCHED), 256, 0, stream>>>(
        xb, w1T, b1, counts, offs, ltok, sched, Hbuf);
    gemm2_kernel<<<dim3(D_DIM / 128, MAX_SCHED), 256, 0, stream>>>(
        Hbuf, w2T, b2, counts, offs, lw, sched, Ybuf);
    combine_kernel<<<N_TOK, 256, 0, stream>>>(Ybuf, slot_of, out);
}

// Round 4
// 789.429 us; speedup vs baseline: 1.0164x; 1.0164x over previous
//
#include <hip/hip_runtime.h>
#include <stdint.h>

// Problem constants (B=4, L=1024 -> N=4096 tokens)
#define N_TOK 4096
#define D_DIM 1024
#define E_EXP 8
#define H_DIM 4096
#define MAX_SCHED 40   // sum ceil(ne/256) <= 8192/256 + 8 = 40

typedef __attribute__((ext_vector_type(8))) short v8s;   // 8 x bf16 (4 VGPRs) MFMA A/B frag
typedef __attribute__((ext_vector_type(4))) float v4f;   // MFMA C/D frag
typedef __attribute__((ext_vector_type(4))) unsigned short u16x4;

static __device__ __forceinline__ unsigned short f2bf(float f) {
    union { float f; unsigned int u; } c; c.f = f;
    unsigned int u = c.u;
    u += 0x7fffu + ((u >> 16) & 1u);   // RNE
    return (unsigned short)(u >> 16);
}
static __device__ __forceinline__ float bf2f(unsigned short h) {
    union { unsigned int u; float f; } c; c.u = ((unsigned int)h) << 16;
    return c.f;
}

// fast tanh-gelu via hw exp: tanh(u) = 1 - 2/(1+e^{2u}); exact at +-inf saturation
static __device__ __forceinline__ float gelu_fast(float x) {
    float u = 0.7978845608028654f * (x + 0.044715f * x * x * x);
    float t = 1.0f - 2.0f / (1.0f + __expf(2.0f * u));
    return 0.5f * x * (1.0f + t);
}

#define GLDS16(g, l)                                                                     \
    __builtin_amdgcn_global_load_lds((const __attribute__((address_space(1))) void*)(g), \
                                     (__attribute__((address_space(3))) void*)(l), 16, 0, 0)

// ---------------- transpose + fp32->bf16: in[e][r][c] -> out[e][c][r], 64x64 tiles ----------------
__global__ __launch_bounds__(256) void transpose_cvt2(const float* __restrict__ in,
                                                      unsigned short* __restrict__ out,
                                                      int R, int C) {
    __shared__ unsigned short tT[64][68];   // [col][row], stride 68 keeps 8B alignment
    int e = blockIdx.z;
    const float* src = in + (size_t)e * R * C;
    unsigned short* dst = out + (size_t)e * R * C;
    int c0 = blockIdx.x * 64, r0 = blockIdx.y * 64;
    int tid = threadIdx.x;
    int col4 = tid & 15, row = tid >> 4;
#pragma unroll
    for (int rr = 0; rr < 4; rr++) {
        int r = rr * 16 + row;
        float4 v = *(const float4*)(src + (size_t)(r0 + r) * C + c0 + col4 * 4);
        tT[col4 * 4 + 0][r] = f2bf(v.x);
        tT[col4 * 4 + 1][r] = f2bf(v.y);
        tT[col4 * 4 + 2][r] = f2bf(v.z);
        tT[col4 * 4 + 3][r] = f2bf(v.w);
    }
    __syncthreads();
    int r4 = tid & 15, cloc = tid >> 4;
#pragma unroll
    for (int cc = 0; cc < 4; cc++) {
        int c = cc * 16 + cloc;
        u16x4 o = *(const u16x4*)(&tT[c][r4 * 4]);
        *(u16x4*)(dst + (size_t)(c0 + c) * R + r0 + r4 * 4) = o;
    }
}

// ---------------- x fp32 -> bf16 ----------------
__global__ void cvt_x_kernel(const float* __restrict__ x, unsigned short* __restrict__ xb, int n4) {
    int i = blockIdx.x * blockDim.x + threadIdx.x;
    if (i < n4) {
        float4 v = ((const float4*)x)[i];
        u16x4 o;
        o.x = f2bf(v.x); o.y = f2bf(v.y); o.z = f2bf(v.z); o.w = f2bf(v.w);
        ((u16x4*)xb)[i] = o;
    }
}

// ---------------- router: fp32 logits, top-2, softmax, counts ----------------
__global__ void router_kernel(const float* __restrict__ x, const float* __restrict__ Wg,
                              const float* __restrict__ bg, float* __restrict__ logits_out,
                              int* __restrict__ tok_e, float* __restrict__ tok_w,
                              int* __restrict__ counts) {
    int wave = threadIdx.x >> 6;
    int lane = threadIdx.x & 63;
    int t = blockIdx.x * 4 + wave;
    if (t >= N_TOK) return;
    const float* xr = x + (size_t)t * D_DIM;
    float acc[8];
#pragma unroll
    for (int e = 0; e < 8; e++) acc[e] = 0.0f;
    for (int d = lane; d < D_DIM; d += 64) {
        float xv = xr[d];
        const float* wr = Wg + d * 8;
        float4 w0 = *(const float4*)wr;
        float4 w1 = *(const float4*)(wr + 4);
        acc[0] += xv * w0.x; acc[1] += xv * w0.y; acc[2] += xv * w0.z; acc[3] += xv * w0.w;
        acc[4] += xv * w1.x; acc[5] += xv * w1.y; acc[6] += xv * w1.z; acc[7] += xv * w1.w;
    }
#pragma unroll
    for (int m = 1; m < 64; m <<= 1) {
#pragma unroll
        for (int e = 0; e < 8; e++) acc[e] += __shfl_xor(acc[e], m, 64);
    }
    if (lane == 0) {
        float lg[8];
#pragma unroll
        for (int e = 0; e < 8; e++) {
            lg[e] = acc[e] + bg[e];
            logits_out[t * 8 + e] = lg[e];
        }
        int i0 = 0; float v0 = lg[0];
        for (int e = 1; e < 8; e++) if (lg[e] > v0) { v0 = lg[e]; i0 = e; }
        int i1 = (i0 == 0) ? 1 : 0; float v1 = lg[i1];
        for (int e = 0; e < 8; e++) {
            if (e == i0 || e == i1) continue;
            if (lg[e] > v1) { v1 = lg[e]; i1 = e; }
        }
        float e1 = expf(v1 - v0);
        float inv = 1.0f / (1.0f + e1);
        tok_e[2 * t]     = i0; tok_w[2 * t]     = inv;
        tok_e[2 * t + 1] = i1; tok_w[2 * t + 1] = e1 * inv;
        atomicAdd(&counts[i0], 1);
        atomicAdd(&counts[i1], 1);
    }
}

// ---------------- exclusive prefix over 8 counts + compact (e, mblk256) schedule ----------------
__global__ void prefix_kernel(const int* __restrict__ counts, int* __restrict__ offsets,
                              int* __restrict__ sched) {
    if (threadIdx.x == 0) {
        int s = 0, idx = 0;
        for (int e = 0; e < E_EXP; e++) {
            offsets[e] = s;
            int ne = counts[e];
            s += ne;
            int nm = (ne + 255) >> 8;
            for (int m = 0; m < nm; m++) sched[1 + idx++] = (e << 16) | m;
        }
        sched[0] = idx;
    }
}

// ---------------- fill per-expert token/weight lists (+slot map) ----------------
__global__ void fill_kernel(const int* __restrict__ tok_e, const float* __restrict__ tok_w,
                            const int* __restrict__ offsets, int* __restrict__ cursors,
                            int* __restrict__ list_tok, float* __restrict__ list_w,
                            int* __restrict__ slot_of) {
    int t = blockIdx.x * blockDim.x + threadIdx.x;
    if (t < N_TOK) {
#pragma unroll
        for (int k = 0; k < 2; k++) {
            int e = tok_e[2 * t + k];
            int pos = atomicAdd(&cursors[e], 1);
            int idx = offsets[e] + pos;
            list_tok[idx] = t;
            list_w[idx] = tok_w[2 * t + k];
            slot_of[2 * t + k] = idx;
        }
    }
}

// ============ GEMM core notes ============
// 256x256 tile, BK=64, 512 threads = 8 waves in a 2(M) x 4(N) grid; each wave owns a
// 128x64 sub-tile -> acc[8][4] v4f, 64 MFMA per wave per K-tile (~310cyc) so the
// per-iteration vmcnt(0) drain is mostly covered by compute (regime: m230 2ph-256²).
// Staging: global_load_lds width=16 into DOUBLE-BUFFERED LDS (2 x 64 KB, 128 KB total).
// Per thread per K-tile: 4 A + 4 B GLDS16; wave wv round t covers rows t*64+wv*8..+7.
// K-loop: issue STAGE(tile k+1) into buf^1, compute tile k from buf, ONE
// __syncthreads() (vmcnt(0)+lgkmcnt(0)+barrier) per iteration.
// XOR swizzle: 16B-chunk g of row r stored at chunk (g ^ (r&7)); applied on the per-lane
// GLOBAL gather address (g = cs ^ lrow) so the LDS dest stays base + lane*16 (glds req).
// Fragment read: chunk = (s*4+q) ^ (r16&7) -> 2 lanes/bank max = free.

// ---------------- GEMM1: Hbuf[slot][H] = gelu(X[tok] @ w1[e] + b1[e]) ----------------
__global__ __launch_bounds__(512, 2) void gemm1_kernel(
    const unsigned short* __restrict__ xb, const unsigned short* __restrict__ w1T,
    const float* __restrict__ b1, const int* __restrict__ counts,
    const int* __restrict__ offsets, const int* __restrict__ list_tok,
    const int* __restrict__ sched, unsigned short* __restrict__ Hbuf) {
    int sm = blockIdx.y;
    if (sm >= sched[0]) return;
    int se = sched[1 + sm];
    int e = se >> 16, mblk = se & 0xffff;
    int ne = counts[e];
    int nblk = blockIdx.x;
    int off = offsets[e];

    __shared__ unsigned short lA[2][256 * 64];
    __shared__ unsigned short lB[2][256 * 64];

    int tid = threadIdx.x;
    int lane = tid & 63, wv = tid >> 6;          // 8 waves
    int wm = wv >> 2, wn = wv & 3;               // 2 x 4 wave grid
    int q = lane >> 4, r16 = lane & 15;
    int lrow = lane >> 3, cs = lane & 7, g = cs ^ lrow;

    const char* aga[4];
    const char* bga[4];
#pragma unroll
    for (int t = 0; t < 4; t++) {
        int ra = t * 64 + wv * 8 + lrow;
        int mrow = mblk * 256 + ra;
        int tok = (mrow < ne) ? list_tok[off + mrow] : list_tok[off];
        aga[t] = (const char*)(xb + (size_t)tok * D_DIM) + g * 16;
        int rb = nblk * 256 + t * 64 + wv * 8 + lrow;
        bga[t] = (const char*)(w1T + ((size_t)e * H_DIM + rb) * D_DIM) + g * 16;
    }

    v4f acc[8][4];
#pragma unroll
    for (int i = 0; i < 8; i++)
#pragma unroll
        for (int j = 0; j < 4; j++) acc[i][j] = (v4f)(0.0f);

    // prologue: stage tile 0 into buffer 0
#pragma unroll
    for (int t = 0; t < 4; t++)
        GLDS16(aga[t], &lA[0][t * 4096 + wv * 512]);
#pragma unroll
    for (int t = 0; t < 4; t++)
        GLDS16(bga[t], &lB[0][t * 4096 + wv * 512]);
    __syncthreads();

    int cur = 0;
    for (int k0 = 0; k0 < D_DIM; k0 += 64) {
        if (k0 + 64 < D_DIM) {   // prefetch next tile into the other buffer
#pragma unroll
            for (int t = 0; t < 4; t++)
                GLDS16(aga[t] + (k0 + 64) * 2, &lA[cur ^ 1][t * 4096 + wv * 512]);
#pragma unroll
            for (int t = 0; t < 4; t++)
                GLDS16(bga[t] + (k0 + 64) * 2, &lB[cur ^ 1][t * 4096 + wv * 512]);
        }
        const unsigned short* A = lA[cur];
        const unsigned short* B = lB[cur];
#pragma unroll
        for (int s = 0; s < 2; s++) {
            v8s af[8], bf[4];
#pragma unroll
            for (int i = 0; i < 8; i++)
                af[i] = *(const v8s*)(&A[(wm * 128 + i * 16 + r16) * 64 + (((s * 4 + q) ^ (r16 & 7)) * 8)]);
#pragma unroll
            for (int j = 0; j < 4; j++)
                bf[j] = *(const v8s*)(&B[(wn * 64 + j * 16 + r16) * 64 + (((s * 4 + q) ^ (r16 & 7)) * 8)]);
#pragma unroll
            for (int i = 0; i < 8; i++)
#pragma unroll
                for (int j = 0; j < 4; j++)
                    acc[i][j] = __builtin_amdgcn_mfma_f32_16x16x32_bf16(af[i], bf[j], acc[i][j], 0, 0, 0);
        }
        __syncthreads();   // drains vmcnt(0)+lgkmcnt(0): next tile resident, buf reads done
        cur ^= 1;
    }

#pragma unroll
    for (int j = 0; j < 4; j++) {
        int col = nblk * 256 + wn * 64 + j * 16 + r16;
        float bias = b1[e * H_DIM + col];
#pragma unroll
        for (int i = 0; i < 8; i++) {
#pragma unroll
            for (int r = 0; r < 4; r++) {
                int m = mblk * 256 + wm * 128 + i * 16 + q * 4 + r;
                if (m < ne) {
                    float v = acc[i][j][r] + bias;
                    Hbuf[(size_t)(off + m) * H_DIM + col] = f2bf(gelu_fast(v));
                }
            }
        }
    }
}

// ---------------- GEMM2: Ybuf[slot][D] = w_slot * (Hbuf[slot] @ w2[e] + b2[e]) (bf16) ----------------
__global__ __launch_bounds__(512, 2) void gemm2_kernel(
    const unsigned short* __restrict__ Hbuf, const unsigned short* __restrict__ w2T,
    const float* __restrict__ b2, const int* __restrict__ counts,
    const int* __restrict__ offsets, const float* __restrict__ list_w,
    const int* __restrict__ sched, unsigned short* __restrict__ Ybuf) {
    int sm = blockIdx.y;
    if (sm >= sched[0]) return;
    int se = sched[1 + sm];
    int e = se >> 16, mblk = se & 0xffff;
    int ne = counts[e];
    int nblk = blockIdx.x;
    int off = offsets[e];

    __shared__ unsigned short lA[2][256 * 64];
    __shared__ unsigned short lB[2][256 * 64];

    int tid = threadIdx.x;
    int lane = tid & 63, wv = tid >> 6;
    int wm = wv >> 2, wn = wv & 3;
    int q = lane >> 4, r16 = lane & 15;
    int lrow = lane >> 3, cs = lane & 7, g = cs ^ lrow;

    const char* aga[4];
    const char* bga[4];
#pragma unroll
    for (int t = 0; t < 4; t++) {
        int ra = t * 64 + wv * 8 + lrow;
        int mrow = mblk * 256 + ra;
        int arow = (mrow < ne) ? mrow : 0;
        aga[t] = (const char*)(Hbuf + (size_t)(off + arow) * H_DIM) + g * 16;
        int rb = nblk * 256 + t * 64 + wv * 8 + lrow;
        bga[t] = (const char*)(w2T + ((size_t)e * D_DIM + rb) * H_DIM) + g * 16;
    }

    v4f acc[8][4];
#pragma unroll
    for (int i = 0; i < 8; i++)
#pragma unroll
        for (int j = 0; j < 4; j++) acc[i][j] = (v4f)(0.0f);

    // prologue: stage tile 0 into buffer 0
#pragma unroll
    for (int t = 0; t < 4; t++)
        GLDS16(aga[t], &lA[0][t * 4096 + wv * 512]);
#pragma unroll
    for (int t = 0; t < 4; t++)
        GLDS16(bga[t], &lB[0][t * 4096 + wv * 512]);
    __syncthreads();

    int cur = 0;
    for (int k0 = 0; k0 < H_DIM; k0 += 64) {
        if (k0 + 64 < H_DIM) {   // prefetch next tile into the other buffer
#pragma unroll
            for (int t = 0; t < 4; t++)
                GLDS16(aga[t] + (k0 + 64) * 2, &lA[cur ^ 1][t * 4096 + wv * 512]);
#pragma unroll
            for (int t = 0; t < 4; t++)
                GLDS16(bga[t] + (k0 + 64) * 2, &lB[cur ^ 1][t * 4096 + wv * 512]);
        }
        const unsigned short* A = lA[cur];
        const unsigned short* B = lB[cur];
#pragma unroll
        for (int s = 0; s < 2; s++) {
            v8s af[8], bf[4];
#pragma unroll
            for (int i = 0; i < 8; i++)
                af[i] = *(const v8s*)(&A[(wm * 128 + i * 16 + r16) * 64 + (((s * 4 + q) ^ (r16 & 7)) * 8)]);
#pragma unroll
            for (int j = 0; j < 4; j++)
                bf[j] = *(const v8s*)(&B[(wn * 64 + j * 16 + r16) * 64 + (((s * 4 + q) ^ (r16 & 7)) * 8)]);
#pragma unroll
            for (int i = 0; i < 8; i++)
#pragma unroll
                for (int j = 0; j < 4; j++)
                    acc[i][j] = __builtin_amdgcn_mfma_f32_16x16x32_bf16(af[i], bf[j], acc[i][j], 0, 0, 0);
        }
        __syncthreads();
        cur ^= 1;
    }

    float bias[4];
#pragma unroll
    for (int j = 0; j < 4; j++)
        bias[j] = b2[e * D_DIM + nblk * 256 + wn * 64 + j * 16 + r16];
#pragma unroll
    for (int i = 0; i < 8; i++) {
#pragma unroll
        for (int r = 0; r < 4; r++) {
            int m = mblk * 256 + wm * 128 + i * 16 + q * 4 + r;
            if (m < ne) {
                int idx = off + m;
                float wgt = list_w[idx];
                unsigned short* yrow = Ybuf + (size_t)idx * D_DIM + nblk * 256 + wn * 64 + r16;
#pragma unroll
                for (int j = 0; j < 4; j++)
                    yrow[j * 16] = f2bf(wgt * (acc[i][j][r] + bias[j]));
            }
        }
    }
}

// ---------------- combine: out[t] = Ybuf[slot_a] + Ybuf[slot_b] ----------------
__global__ void combine_kernel(const unsigned short* __restrict__ Ybuf,
                               const int* __restrict__ slot_of, float* __restrict__ out) {
    int t = blockIdx.x;
    int sa = slot_of[2 * t], sb = slot_of[2 * t + 1];
    const u16x4* ya = (const u16x4*)(Ybuf + (size_t)sa * D_DIM);
    const u16x4* yb = (const u16x4*)(Ybuf + (size_t)sb * D_DIM);
    float4* o = (float4*)(out + (size_t)t * D_DIM);
    int i = threadIdx.x;   // 256 threads x float4 = 1024 floats
    u16x4 a = ya[i], b = yb[i];
    float4 r;
    r.x = bf2f(a.x) + bf2f(b.x);
    r.y = bf2f(a.y) + bf2f(b.y);
    r.z = bf2f(a.z) + bf2f(b.z);
    r.w = bf2f(a.w) + bf2f(b.w);
    o[i] = r;
}

// ---------------- launch ----------------
extern "C" void kernel_launch(void* const* d_in, const int* in_sizes, int n_in,
                              void* d_out, int out_size, void* d_ws, size_t ws_size,
                              hipStream_t stream) {
    const float* x  = (const float*)d_in[0];
    const float* Wg = (const float*)d_in[1];
    const float* bg = (const float*)d_in[2];
    const float* w1 = (const float*)d_in[3];
    const float* b1 = (const float*)d_in[4];
    const float* w2 = (const float*)d_in[5];
    const float* b2 = (const float*)d_in[6];

    float* out = (float*)d_out;                       // [N_TOK * D_DIM]
    float* logits = out + (size_t)N_TOK * D_DIM;      // [N_TOK * E_EXP]

    char* ws = (char*)d_ws;
    // workspace layout (bytes)
    const size_t o_counts  = 0;                         // 8 i32
    const size_t o_cursors = 32;                        // 8 i32
    const size_t o_offsets = 64;                        // 8 i32
    const size_t o_toke    = 128;                       // 8192 i32
    const size_t o_tokw    = o_toke + 32768;
    const size_t o_ltok    = o_tokw + 32768;            // 8448 i32
    const size_t o_lw      = o_ltok + 33792;
    const size_t o_slot    = o_lw + 33792;              // 8192 i32
    const size_t o_sched   = o_slot + 32768;            // 1 + 40 i32 (compact schedule)
    const size_t o_xb      = 196608;                                      // 8 MiB
    const size_t o_w1T     = o_xb + (size_t)N_TOK * D_DIM * 2;            // 64 MiB
    const size_t o_w2T     = o_w1T + (size_t)E_EXP * D_DIM * H_DIM * 2;   // 64 MiB
    const size_t o_Hbuf    = o_w2T + (size_t)E_EXP * D_DIM * H_DIM * 2;   // 64 MiB
    const size_t o_Ybuf    = o_Hbuf + (size_t)8192 * H_DIM * 2;           // 16 MiB

    int*            counts  = (int*)(ws + o_counts);
    int*            cursors = (int*)(ws + o_cursors);
    int*            offs    = (int*)(ws + o_offsets);
    int*            tok_e   = (int*)(ws + o_toke);
    float*          tok_w   = (float*)(ws + o_tokw);
    int*            ltok    = (int*)(ws + o_ltok);
    float*          lw      = (float*)(ws + o_lw);
    int*            slot_of = (int*)(ws + o_slot);
    int*            sched   = (int*)(ws + o_sched);
    unsigned short* xb      = (unsigned short*)(ws + o_xb);
    unsigned short* w1T     = (unsigned short*)(ws + o_w1T);
    unsigned short* w2T     = (unsigned short*)(ws + o_w2T);
    unsigned short* Hbuf    = (unsigned short*)(ws + o_Hbuf);
    unsigned short* Ybuf    = (unsigned short*)(ws + o_Ybuf);

    (void)hipMemsetAsync(ws, 0, 128, stream);   // counts/cursors/offsets

    // w1 [E][D][H] -> w1T [E][H][D]; w2 [E][H][D] -> w2T [E][D][H]
    transpose_cvt2<<<dim3(H_DIM / 64, D_DIM / 64, E_EXP), 256, 0, stream>>>(w1, w1T, D_DIM, H_DIM);
    transpose_cvt2<<<dim3(D_DIM / 64, H_DIM / 64, E_EXP), 256, 0, stream>>>(w2, w2T, H_DIM, D_DIM);
    cvt_x_kernel<<<(N_TOK * D_DIM / 4 + 255) / 256, 256, 0, stream>>>(x, xb, N_TOK * D_DIM / 4);

    router_kernel<<<N_TOK / 4, 256, 0, stream>>>(x, Wg, bg, logits, tok_e, tok_w, counts);
    prefix_kernel<<<1, 64, 0, stream>>>(counts, offs, sched);
    fill_kernel<<<N_TOK / 256, 256, 0, stream>>>(tok_e, tok_w, offs, cursors, ltok, lw, slot_of);

    gemm1_kernel<<<dim3(H_DIM / 256, MAX_SCHED), 512, 0, stream>>>(
        xb, w1T, b1, counts, offs, ltok, sched, Hbuf);
    gemm2_kernel<<<dim3(D_DIM / 256, MAX_SCHED), 512, 0, stream>>>(
        Hbuf, w2T, b2, counts, offs, lw, sched, Ybuf);
    combine_kernel<<<N_TOK, 256, 0, stream>>>(Ybuf, slot_of, out);
}